// Round 15
// baseline (320.772 us; speedup 1.0000x reference)
//
#include <hip/hip_runtime.h>
#include <hip/hip_bf16.h>
#include <stdint.h>

// CRF nllh = sum_b (logZ_b - score_b).   SINGLE FUSED KERNEL + 16B memset.
// logZ via chunked parallel scan in probability domain:
//   alpha_t = alpha_{t-1} * Q_t,  Q_t[i][j] = exp(trans[i][j]/w_{t-1} + em_t[j])
// 32 chunks of 64 steps: chunk computes X_c = (Q_{t0}..Q_{t1-1})^T with
// 32x32x16 bf16 MFMA pairs (X <- Q^T X, K=32 via C-chaining).
// k-permutation sigma folded into A-side constants => D reg-pairs ARE the next
// B operands verbatim. Q entries built as bf16 BITS via magic Schraudolph:
//   f = fma(tpre, 1/w, em*KSC + SBIAS + 2^23); bf16bits = low16(bits(f))
// ILP=4 phased step4 (A-builds -> B-packs -> 4 MFMA1 -> 4 MFMA2), LB(256,2),
// VGPR~76 (ILP=8 spills -- do not revisit).
// FUSION: per-dispatch overhead measured ~25-40us (R2->R3 zero_out datapoint),
// so combine is fused behind an in-kernel global barrier. Grid=512 blocks =
// exactly 2/CU capacity under LB(256,2) => all blocks co-resident => spin-wait
// barrier is deadlock-free. Wave 0 of blocks 0..255 runs combine for batch
// b=blockIdx (depth-1 prefetch -- depth-4 ring regressed, do not revisit).
// Score partials + logZ accumulate into d_ws accum; block 0 plain-stores the
// final sum to d_out (no out-memset). Counters/accum zeroed by a 16B memset.
// Fences: __builtin_amdgcn_fence (NOT __hip_atomic_fence -- doesn't exist).

#define T_DIM 2048
#define B_DIM 256
#define M_DIM 32
#define CHUNKS 32
#define CLEN 64
#define NBLOCKS ((CHUNKS * B_DIM) / 16)   /* 512 */
#define KSC 184.6649652337873f      /* 128 / ln2 */
#define SBIAS2 12599160.66f         /* 2^23 + 127*128 - 7.34 (log-mean center) */

typedef __attribute__((ext_vector_type(8))) short short8;
typedef __attribute__((ext_vector_type(16))) float f32x16;

__device__ __forceinline__ int pack_bf16(float lo, float hi) {
  union { float f; uint32_t u; } a, b;
  a.f = lo; b.f = hi;
  return (int)__builtin_amdgcn_perm(b.u, a.u, 0x07060302u);
}

__device__ __forceinline__ int pack_lo16(int lo, int hi) {
  return (int)__builtin_amdgcn_perm((uint32_t)hi, (uint32_t)lo, 0x05040100u);
}

__device__ __forceinline__ float bcast_lane(float v, int idx) {
  return __int_as_float(__builtin_amdgcn_readlane(__float_as_int(v), idx));
}

__device__ __forceinline__ uint32_t ld_cnt(uint32_t* p) {
  return __hip_atomic_load(p, __ATOMIC_RELAXED, __HIP_MEMORY_SCOPE_AGENT);
}

// 256 threads = 4 waves; each wave handles units 4w..4w+3 (chunk c, batches
// bb..bb+3). After the barrier, wave 0 of blocks 0..255 combines batch b.
__global__ __launch_bounds__(256, 2) void chunk_kernel(
    const float* __restrict__ em, const int* __restrict__ tags,
    const float* __restrict__ wt, const int* __restrict__ mask,
    const float* __restrict__ trans, const float* __restrict__ startt,
    const float* __restrict__ endt,
    uint32_t* __restrict__ ctrl,      // [0]=cnt1 [1]=cnt2 [2]=accum(float)
    float* __restrict__ offs, uint32_t* __restrict__ mats,
    float* __restrict__ out)
{
  float* accum = (float*)(ctrl + 2);
  int tid = threadIdx.x;
  int lane = tid & 63;
  int h = lane >> 5;        // wave half
  int r = lane & 31;        // A-row / B-col / D-col index
  int wid = blockIdx.x * 4 + (tid >> 6);
  int u0 = 4 * wid;                      // first unit = c*B + bb
  int bb = u0 & (B_DIM - 1);             // base batch (multiple of 4)
  int c = u0 >> 8;
  int t0 = 1 + c * CLEN;
  int t1 = t0 + CLEN; if (t1 > T_DIM) t1 = T_DIM;

  // A-side transition constants with the k-permutation sigma folded in
  float tpre[16];
#pragma unroll
  for (int j = 0; j < 8; ++j) {
    int row = ((j < 4) ? j : j + 4) + 4 * h;
    tpre[j]     = trans[row * 32 + r] * KSC;
    tpre[8 + j] = trans[(row + 16) * 32 + r] * KSC;
  }

  // hoisted per-chunk scalars: lane s <-> step t0+s
  int tw = t0 - 1 + lane; if (tw > T_DIM - 1) tw = T_DIM - 1;
  int tmk = t0 + lane; if (tmk > T_DIM - 1) tmk = T_DIM - 1;
  float rwv[4];
  uint64_t mk[4];
  uint64_t valid = (t1 - t0 >= 64) ? ~0ull : ((1ull << (t1 - t0)) - 1ull);
#pragma unroll
  for (int ch = 0; ch < 4; ++ch) {
    rwv[ch] = __builtin_amdgcn_rcpf(wt[tw * B_DIM + bb + ch]);
    mk[ch] = __ballot(mask[tmk * B_DIM + bb + ch] != 0) & valid;
  }

  // X = identity in 32x32 D/C layout: reg p holds row (p&3)+8*(p>>2)+4h, col r
  f32x16 X[4];
#pragma unroll
  for (int p = 0; p < 16; ++p) {
    float v = (((p & 3) + 8 * (p >> 2) + 4 * h) == r) ? 1.f : 0.f;
    X[0][p] = v; X[1][p] = v; X[2][p] = v; X[3][p] = v;
  }
  f32x16 z;
#pragma unroll
  for (int u = 0; u < 16; ++u) z[u] = 0.f;

  float off2[4] = {0.f, 0.f, 0.f, 0.f};

  auto step4 = [&](const float* e4, int s) {
    float rw0 = bcast_lane(rwv[0], s), rw1 = bcast_lane(rwv[1], s);
    float rw2 = bcast_lane(rwv[2], s), rw3 = bcast_lane(rwv[3], s);
    float rw[4] = {rw0, rw1, rw2, rw3};
    union { int i[4]; short8 s8; } af1[4], af2[4], b1[4], b2[4];
#pragma unroll
    for (int ch = 0; ch < 4; ++ch) {
      float e = fmaf(e4[ch], KSC, SBIAS2);
      float qf[16];
#pragma unroll
      for (int j = 0; j < 16; ++j)
        qf[j] = fmaf(tpre[j], rw[ch], e);
#pragma unroll
      for (int u = 0; u < 4; ++u) {
        af1[ch].i[u] = pack_lo16(__float_as_int(qf[2 * u]),     __float_as_int(qf[2 * u + 1]));
        af2[ch].i[u] = pack_lo16(__float_as_int(qf[8 + 2 * u]), __float_as_int(qf[8 + 2 * u + 1]));
      }
    }
#pragma unroll
    for (int ch = 0; ch < 4; ++ch)
#pragma unroll
      for (int u = 0; u < 4; ++u) {
        b1[ch].i[u] = pack_bf16(X[ch][2 * u],     X[ch][2 * u + 1]);
        b2[ch].i[u] = pack_bf16(X[ch][8 + 2 * u], X[ch][8 + 2 * u + 1]);
      }
    f32x16 d[4];
#pragma unroll
    for (int ch = 0; ch < 4; ++ch)
      d[ch] = __builtin_amdgcn_mfma_f32_32x32x16_bf16(af1[ch].s8, b1[ch].s8, z, 0, 0, 0);
#pragma unroll
    for (int ch = 0; ch < 4; ++ch)
      X[ch] = __builtin_amdgcn_mfma_f32_32x32x16_bf16(af2[ch].s8, b2[ch].s8, d[ch], 0, 0, 0);
  };

  auto stepOne = [&](f32x16& Xc, float e_em, float rw) {
    float e = fmaf(e_em, KSC, SBIAS2);
    float qf[16];
#pragma unroll
    for (int j = 0; j < 16; ++j)
      qf[j] = fmaf(tpre[j], rw, e);
    union { int i[4]; short8 s8; } af1, af2, b1_, b2_;
#pragma unroll
    for (int u = 0; u < 4; ++u) {
      af1.i[u] = pack_lo16(__float_as_int(qf[2 * u]),     __float_as_int(qf[2 * u + 1]));
      af2.i[u] = pack_lo16(__float_as_int(qf[8 + 2 * u]), __float_as_int(qf[8 + 2 * u + 1]));
      b1_.i[u] = pack_bf16(Xc[2 * u],     Xc[2 * u + 1]);
      b2_.i[u] = pack_bf16(Xc[8 + 2 * u], Xc[8 + 2 * u + 1]);
    }
    f32x16 d = __builtin_amdgcn_mfma_f32_32x32x16_bf16(af1.s8, b1_.s8, z, 0, 0, 0);
    Xc = __builtin_amdgcn_mfma_f32_32x32x16_bf16(af2.s8, b2_.s8, d, 0, 0, 0);
  };

  auto rescale = [&](f32x16& Xc, float& o2) {
    float mx = Xc[0];
#pragma unroll
    for (int u = 1; u < 16; ++u) mx = fmaxf(mx, Xc[u]);
#pragma unroll
    for (int off = 1; off < 64; off <<= 1) mx = fmaxf(mx, __shfl_xor(mx, off));
    float sc = __builtin_amdgcn_rcpf(mx);
    o2 += __builtin_amdgcn_logf(mx);  // log2
#pragma unroll
    for (int u = 0; u < 16; ++u) Xc[u] *= sc;
  };

  bool fast = (t1 - t0 == 64) && (mk[0] == ~0ull) && (mk[1] == ~0ull)
            && (mk[2] == ~0ull) && (mk[3] == ~0ull);

  if (fast) {
    // FAST PATH: branch-free, groups of 8 steps
    float e[4][4], n[4][4];
#pragma unroll
    for (int ch = 0; ch < 4; ++ch)
#pragma unroll
      for (int u = 0; u < 4; ++u)
        e[ch][u] = em[((size_t)((t0 + 2 * u + h) * B_DIM + bb + ch)) * 32 + r];
    for (int g = 0; g < 8; ++g) {
      int tg = t0 + 8 * (g + 1);
#pragma unroll
      for (int ch = 0; ch < 4; ++ch)
#pragma unroll
        for (int u = 0; u < 4; ++u) {
          int tt = tg + 2 * u + h; if (tt > T_DIM - 1) tt = T_DIM - 1;
          n[ch][u] = em[((size_t)(tt * B_DIM + bb + ch)) * 32 + r];
        }
#pragma unroll
      for (int u = 0; u < 4; ++u) {
        int sA = 8 * g + 2 * u, sB = sA + 1;
        float eA[4], eB[4];
#pragma unroll
        for (int ch = 0; ch < 4; ++ch) {
          float sw = __shfl_xor(e[ch][u], 32);
          eA[ch] = h ? sw : e[ch][u];
          eB[ch] = h ? e[ch][u] : sw;
        }
        step4(eA, sA);
        step4(eB, sB);
      }
#pragma unroll
      for (int ch = 0; ch < 4; ++ch) rescale(X[ch], off2[ch]);
#pragma unroll
      for (int ch = 0; ch < 4; ++ch)
#pragma unroll
        for (int u = 0; u < 4; ++u) e[ch][u] = n[ch][u];
    }
  } else {
    // GENERAL PATH: per-step mask guards
    float emv[4], emp[4];
#pragma unroll
    for (int ch = 0; ch < 4; ++ch)
      emv[ch] = em[((size_t)((t0 + h) * B_DIM + bb + ch)) * 32 + r];
    int tpf = t0 + 2 + h; if (tpf > T_DIM - 1) tpf = T_DIM - 1;
#pragma unroll
    for (int ch = 0; ch < 4; ++ch)
      emp[ch] = em[((size_t)(tpf * B_DIM + bb + ch)) * 32 + r];

    for (int it = 0; it < CLEN / 2; ++it) {
      int tn = t0 + 2 * it + 4 + h; if (tn > T_DIM - 1) tn = T_DIM - 1;
      float emn[4];
#pragma unroll
      for (int ch = 0; ch < 4; ++ch)
        emn[ch] = em[((size_t)(tn * B_DIM + bb + ch)) * 32 + r];

      int sA = 2 * it, sB = sA + 1;
#pragma unroll
      for (int ch = 0; ch < 4; ++ch) {
        float sw = __shfl_xor(emv[ch], 32);
        if ((mk[ch] >> sA) & 1)
          stepOne(X[ch], h ? sw : emv[ch], bcast_lane(rwv[ch], sA));
        if ((t0 + sB < t1) && ((mk[ch] >> sB) & 1))
          stepOne(X[ch], h ? emv[ch] : sw, bcast_lane(rwv[ch], sB));
      }

      if ((it & 3) == 3) {
#pragma unroll
        for (int ch = 0; ch < 4; ++ch) rescale(X[ch], off2[ch]);
      }
#pragma unroll
      for (int ch = 0; ch < 4; ++ch) { emv[ch] = emp[ch]; emp[ch] = emn[ch]; }
    }
  }

  // store X as packed bf16 row-pairs
#pragma unroll
  for (int ch = 0; ch < 4; ++ch) {
    uint32_t* mp = mats + (size_t)(u0 + ch) * 512;
#pragma unroll
    for (int u = 0; u < 8; ++u) {
      int pairIdx = (u & 1) + (u >> 1) * 4 + 2 * h;
      mp[pairIdx * 32 + r] = (uint32_t)pack_bf16(X[ch][2 * u], X[ch][2 * u + 1]);
    }
  }
  if (lane == 0) {
#pragma unroll
    for (int ch = 0; ch < 4; ++ch) offs[u0 + ch] = off2[ch];
  }

  // score epilogue: one lane per timestep, all 4 chains -> accum
  int t = t0 + lane;
  float ssc = 0.f;
  if (t < t1) {
#pragma unroll
    for (int ch = 0; ch < 4; ++ch) {
      int b = bb + ch;
      int mkc  = mask[t * B_DIM + b];
      int mkn  = (t + 1 < T_DIM) ? mask[(t + 1) * B_DIM + b] : 0;
      int tg   = mkc ? tags[t * B_DIM + b] : 1;
      int mkp  = mask[(t - 1) * B_DIM + b];
      int tgp  = mkp ? tags[(t - 1) * B_DIM + b] : 1;
      if (mkc)
        ssc += em[(size_t)(t * B_DIM + b) * 32 + tg]
             + trans[tgp * 32 + tg] * __builtin_amdgcn_rcpf(wt[(t - 1) * B_DIM + b]);
      if (mkc && !mkn) ssc += endt[tg];
    }
  }
#pragma unroll
  for (int off = 32; off; off >>= 1) ssc += __shfl_xor(ssc, off);
  if (lane == 0) atomicAdd(accum, -ssc);

  // ======== global barrier 1: all NBLOCKS blocks finished chunk phase =======
  __syncthreads();
  if (tid == 0) {
    __builtin_amdgcn_fence(__ATOMIC_RELEASE, "agent");
    atomicAdd(&ctrl[0], 1u);
  }

  // combine: wave 0 of blocks 0..255, batch b = blockIdx.x
  if (blockIdx.x >= B_DIM || tid >= 64) return;
  {
    while (ld_cnt(&ctrl[0]) < (uint32_t)NBLOCKS) __builtin_amdgcn_s_sleep(8);
    __builtin_amdgcn_fence(__ATOMIC_ACQUIRE, "agent");

    const float INV_LN2 = 1.44269504088896340736f;
    const float LN2 = 0.69314718055994530942f;
    int b = blockIdx.x;
    int j = lane & 31;
    int hh = lane >> 5;
    int jp = j >> 1, jh = j & 1;

    float a0 = (startt[j] + em[(size_t)b * 32 + j]) * INV_LN2;  // log2 domain
    float c0 = a0;
#pragma unroll
    for (int off = 1; off < 32; off <<= 1) c0 = fmaxf(c0, __shfl_xor(c0, off));
    float av = __builtin_amdgcn_exp2f(a0 - c0);
    float acc = c0;

    // depth-1 prefetch of chunk data
    const uint4* xr0 = (const uint4*)(mats + (size_t)b * 512 + jp * 32 + 16 * hh);
    uint4 nv0 = xr0[0], nv1 = xr0[1];
    float noff = offs[b];

    for (int cc = 0; cc < CHUNKS; ++cc) {
      uint4 v0 = nv0, v1 = nv1;
      float offc = noff;
      int cn = (cc + 1 < CHUNKS) ? cc + 1 : cc;
      const uint4* xrn = (const uint4*)(mats + (size_t)(cn * B_DIM + b) * 512 + jp * 32 + 16 * hh);
      nv0 = xrn[0]; nv1 = xrn[1];
      noff = offs[cn * B_DIM + b];

      float x[8];
      uint32_t w0[4] = {v0.x, v0.y, v0.z, v0.w};
      uint32_t w1[4] = {v1.x, v1.y, v1.z, v1.w};
#pragma unroll
      for (int e = 0; e < 4; ++e) {
        uint32_t bits0 = jh ? (w0[e] & 0xFFFF0000u) : (w0[e] << 16);
        uint32_t bits1 = jh ? (w1[e] & 0xFFFF0000u) : (w1[e] << 16);
        union { uint32_t uu; float f; } cv0, cv1;
        cv0.uu = bits0; cv1.uu = bits1;
        x[e] = cv0.f; x[4 + e] = cv1.f;
      }
      float s0 = 0.f, s1 = 0.f;
#pragma unroll
      for (int i = 0; i < 4; ++i) {
        s0 = fmaf(x[i],     __shfl(av, 16 * hh + i),     s0);
        s1 = fmaf(x[4 + i], __shfl(av, 16 * hh + 4 + i), s1);
      }
      float an = s0 + s1;
      an += __shfl_xor(an, 32);   // combine the two column-halves
      float mx = an;
#pragma unroll
      for (int off = 1; off < 32; off <<= 1) mx = fmaxf(mx, __shfl_xor(mx, off));
      av = an * __builtin_amdgcn_rcpf(mx);
      acc += __builtin_amdgcn_logf(mx) + offc;
    }

    float sv = av * __builtin_amdgcn_exp2f(endt[j] * INV_LN2);
#pragma unroll
    for (int off = 1; off < 32; off <<= 1) sv += __shfl_xor(sv, off);
    if (lane == 0) {
      float logZ = (acc + __builtin_amdgcn_logf(sv)) * LN2;
      // t=0 gold-path score terms
      int mk0 = mask[b];
      int tg0 = mk0 ? tags[b] : 1;
      float s0 = startt[tg0] + (mk0 ? em[(size_t)b * 32 + tg0] : 0.f);
      int mk1 = mask[B_DIM + b];
      if (mk0 && !mk1) s0 += endt[tg0];
      atomicAdd(accum, logZ - s0);
      __builtin_amdgcn_fence(__ATOMIC_RELEASE, "agent");
      atomicAdd(&ctrl[1], 1u);
    }
  }

  // ======== barrier 2 + final store: block 0 lane 0 =========================
  if (blockIdx.x == 0 && tid == 0) {
    while (ld_cnt(&ctrl[1]) < (uint32_t)B_DIM) __builtin_amdgcn_s_sleep(8);
    __builtin_amdgcn_fence(__ATOMIC_ACQUIRE, "agent");
    out[0] = __hip_atomic_load((float*)(ctrl + 2), __ATOMIC_RELAXED,
                               __HIP_MEMORY_SCOPE_AGENT);
  }
}

extern "C" void kernel_launch(void* const* d_in, const int* in_sizes, int n_in,
                              void* d_out, int out_size, void* d_ws, size_t ws_size,
                              hipStream_t stream) {
  const float* em   = (const float*)d_in[0];
  const int*   tags = (const int*)d_in[1];
  const float* wt   = (const float*)d_in[2];
  const int*   mask = (const int*)d_in[3];
  const float* tr   = (const float*)d_in[4];
  const float* stt  = (const float*)d_in[5];
  const float* ent  = (const float*)d_in[6];
  float* out = (float*)d_out;

  uint32_t* ctrl = (uint32_t*)d_ws;                 // cnt1, cnt2, accum, pad
  float* offs = (float*)d_ws + 4;                   // CHUNKS*B floats (32 KB)
  uint32_t* mats = (uint32_t*)(offs + CHUNKS * B_DIM); // CHUNKS*B*512 u32 (~16.8 MB)

  (void)hipMemsetAsync(ctrl, 0, 16, stream);
  chunk_kernel<<<NBLOCKS, 256, 0, stream>>>(em, tags, wt, mask, tr, stt, ent,
                                            ctrl, offs, mats, out);
}

// Round 16
// 179.299 us; speedup vs baseline: 1.7890x; 1.7890x over previous
//
#include <hip/hip_runtime.h>
#include <hip/hip_bf16.h>
#include <stdint.h>

// CRF nllh = sum_b (logZ_b - score_b).      BEST CONFIG (R12: 181.6us).
// logZ via chunked parallel scan in probability domain:
//   alpha_t = alpha_{t-1} * Q_t,  Q_t[i][j] = exp(trans[i][j]/w_{t-1} + em_t[j])
// 32 chunks of 64 steps: chunk computes X_c = (Q_{t0}..Q_{t1-1})^T with
// 32x32x16 bf16 MFMA pairs (X <- Q^T X, K=32 via C-chaining).
// k-permutation sigma folded into A-side constants => D reg-pairs ARE the next
// B operands verbatim (zero cross-lane exchange per step).
// Q entries built as bf16 BITS via magic-constant Schraudolph:
//   f = fma(tpre, 1/w, em*KSC + SBIAS + 2^23); bf16bits = low16(bits(f))
// ILP=4 with EXPLICIT PHASE INTERLEAVING (step4): A-builds -> B-packs ->
// 4 MFMA1 -> 4 MFMA2; LB(256,2), VGPR~76.
// Negative results (do NOT revisit): ILP=8 spills (VGPR 256 cap, 2x WRITE);
// CHUNKS=64 doubles per-chunk fixed cost (net -25%); depth-4 combine prefetch
// ring -30us; fused single-kernel with spin barrier -140us (cross-XCD
// cacheline contention on the counter); cross-wave TLP < in-wave ILP.
// wt/mask hoisted per chunk (readlane broadcast + ballot bitmask); em rows
// split-half (lanes 0-31 row t, lanes 32-63 row t+1), group-of-8 prefetch.
// Rescale every 8 steps (log2 offset). Score = lane-per-step epilogue.

#define T_DIM 2048
#define B_DIM 256
#define M_DIM 32
#define CHUNKS 32
#define CLEN 64
#define KSC 184.6649652337873f      /* 128 / ln2 */
#define SBIAS2 12599160.66f         /* 2^23 + 127*128 - 7.34 (log-mean center) */

typedef __attribute__((ext_vector_type(8))) short short8;
typedef __attribute__((ext_vector_type(16))) float f32x16;

__device__ __forceinline__ int pack_bf16(float lo, float hi) {
  union { float f; uint32_t u; } a, b;
  a.f = lo; b.f = hi;
  // result = bf16(lo) | bf16(hi)<<16 (truncation rounding)
  return (int)__builtin_amdgcn_perm(b.u, a.u, 0x07060302u);
}

__device__ __forceinline__ int pack_lo16(int lo, int hi) {
  // (lo & 0xffff) | (hi << 16)
  return (int)__builtin_amdgcn_perm((uint32_t)hi, (uint32_t)lo, 0x05040100u);
}

__device__ __forceinline__ float bcast_lane(float v, int idx) {
  // wave-uniform broadcast: v_readlane -> SGPR (folds as scalar operand)
  return __int_as_float(__builtin_amdgcn_readlane(__float_as_int(v), idx));
}

// ---------------- chunk matrix products (MFMA) + score epilogue ----------------
// 256 threads = 4 waves; each wave handles units 4w..4w+3 (= chunk c,
// batches bb..bb+3).
__global__ __launch_bounds__(256, 2) void chunk_kernel(
    const float* __restrict__ em, const int* __restrict__ tags,
    const float* __restrict__ wt, const int* __restrict__ mask,
    const float* __restrict__ trans, const float* __restrict__ endt,
    uint32_t* __restrict__ mats, float* __restrict__ offs,
    float* __restrict__ out)
{
  int tid = threadIdx.x;
  int lane = tid & 63;
  int h = lane >> 5;        // wave half
  int r = lane & 31;        // A-row / B-col / D-col index
  int wid = blockIdx.x * 4 + (tid >> 6);
  int u0 = 4 * wid;                      // first unit = c*B + bb
  int bb = u0 & (B_DIM - 1);             // base batch (multiple of 4)
  int c = u0 >> 8;
  int t0 = 1 + c * CLEN;
  int t1 = t0 + CLEN; if (t1 > T_DIM) t1 = T_DIM;

  // A-side transition constants with the k-permutation sigma folded in:
  // sigma1(8h+j) = (j<4 ? j : j+4) + 4h ; sigma2 = sigma1 + 16  (shared chains)
  float tpre[16];
#pragma unroll
  for (int j = 0; j < 8; ++j) {
    int row = ((j < 4) ? j : j + 4) + 4 * h;
    tpre[j]     = trans[row * 32 + r] * KSC;
    tpre[8 + j] = trans[(row + 16) * 32 + r] * KSC;
  }

  // ---- hoisted per-chunk scalars: lane s <-> step t0+s ----
  int tw = t0 - 1 + lane; if (tw > T_DIM - 1) tw = T_DIM - 1;
  int tmk = t0 + lane; if (tmk > T_DIM - 1) tmk = T_DIM - 1;
  float rwv[4];
  uint64_t mk[4];
  uint64_t valid = (t1 - t0 >= 64) ? ~0ull : ((1ull << (t1 - t0)) - 1ull);
#pragma unroll
  for (int ch = 0; ch < 4; ++ch) {
    rwv[ch] = __builtin_amdgcn_rcpf(wt[tw * B_DIM + bb + ch]);
    mk[ch] = __ballot(mask[tmk * B_DIM + bb + ch] != 0) & valid;
  }

  // X = identity in 32x32 D/C layout: reg p holds row (p&3)+8*(p>>2)+4h, col r
  f32x16 X[4];
#pragma unroll
  for (int p = 0; p < 16; ++p) {
    float v = (((p & 3) + 8 * (p >> 2) + 4 * h) == r) ? 1.f : 0.f;
    X[0][p] = v; X[1][p] = v; X[2][p] = v; X[3][p] = v;
  }
  f32x16 z;
#pragma unroll
  for (int u = 0; u < 16; ++u) z[u] = 0.f;

  float off2[4] = {0.f, 0.f, 0.f, 0.f};

  // phased 4-chain step: A-builds, B-packs, MFMA1 x4, MFMA2 x4
  auto step4 = [&](const float* e4, int s) {
    float rw0 = bcast_lane(rwv[0], s), rw1 = bcast_lane(rwv[1], s);
    float rw2 = bcast_lane(rwv[2], s), rw3 = bcast_lane(rwv[3], s);
    float rw[4] = {rw0, rw1, rw2, rw3};
    union { int i[4]; short8 s8; } af1[4], af2[4], b1[4], b2[4];
    // Phase 1: A fragments (X-independent)
#pragma unroll
    for (int ch = 0; ch < 4; ++ch) {
      float e = fmaf(e4[ch], KSC, SBIAS2);
      float qf[16];
#pragma unroll
      for (int j = 0; j < 16; ++j)
        qf[j] = fmaf(tpre[j], rw[ch], e);
#pragma unroll
      for (int u = 0; u < 4; ++u) {
        af1[ch].i[u] = pack_lo16(__float_as_int(qf[2 * u]),     __float_as_int(qf[2 * u + 1]));
        af2[ch].i[u] = pack_lo16(__float_as_int(qf[8 + 2 * u]), __float_as_int(qf[8 + 2 * u + 1]));
      }
    }
    // Phase 2: B packs (X's D reg-pairs verbatim; sigma absorbed the mismatch)
#pragma unroll
    for (int ch = 0; ch < 4; ++ch)
#pragma unroll
      for (int u = 0; u < 4; ++u) {
        b1[ch].i[u] = pack_bf16(X[ch][2 * u],     X[ch][2 * u + 1]);
        b2[ch].i[u] = pack_bf16(X[ch][8 + 2 * u], X[ch][8 + 2 * u + 1]);
      }
    // Phase 3: MFMA1, all chains (independent)
    f32x16 d[4];
#pragma unroll
    for (int ch = 0; ch < 4; ++ch)
      d[ch] = __builtin_amdgcn_mfma_f32_32x32x16_bf16(af1[ch].s8, b1[ch].s8, z, 0, 0, 0);
    // Phase 4: MFMA2, all chains
#pragma unroll
    for (int ch = 0; ch < 4; ++ch)
      X[ch] = __builtin_amdgcn_mfma_f32_32x32x16_bf16(af2[ch].s8, b2[ch].s8, d[ch], 0, 0, 0);
  };

  auto stepOne = [&](f32x16& Xc, float e_em, float rw) {
    float e = fmaf(e_em, KSC, SBIAS2);
    float qf[16];
#pragma unroll
    for (int j = 0; j < 16; ++j)
      qf[j] = fmaf(tpre[j], rw, e);
    union { int i[4]; short8 s8; } af1, af2, b1_, b2_;
#pragma unroll
    for (int u = 0; u < 4; ++u) {
      af1.i[u] = pack_lo16(__float_as_int(qf[2 * u]),     __float_as_int(qf[2 * u + 1]));
      af2.i[u] = pack_lo16(__float_as_int(qf[8 + 2 * u]), __float_as_int(qf[8 + 2 * u + 1]));
      b1_.i[u] = pack_bf16(Xc[2 * u],     Xc[2 * u + 1]);
      b2_.i[u] = pack_bf16(Xc[8 + 2 * u], Xc[8 + 2 * u + 1]);
    }
    f32x16 d = __builtin_amdgcn_mfma_f32_32x32x16_bf16(af1.s8, b1_.s8, z, 0, 0, 0);
    Xc = __builtin_amdgcn_mfma_f32_32x32x16_bf16(af2.s8, b2_.s8, d, 0, 0, 0);
  };

  auto rescale = [&](f32x16& Xc, float& o2) {
    float mx = Xc[0];
#pragma unroll
    for (int u = 1; u < 16; ++u) mx = fmaxf(mx, Xc[u]);
#pragma unroll
    for (int off = 1; off < 64; off <<= 1) mx = fmaxf(mx, __shfl_xor(mx, off));
    float sc = __builtin_amdgcn_rcpf(mx);
    o2 += __builtin_amdgcn_logf(mx);  // log2
#pragma unroll
    for (int u = 0; u < 16; ++u) Xc[u] *= sc;
  };

  bool fast = (t1 - t0 == 64) && (mk[0] == ~0ull) && (mk[1] == ~0ull)
            && (mk[2] == ~0ull) && (mk[3] == ~0ull);

  if (fast) {
    // ================= FAST PATH: branch-free, groups of 8 steps ============
    float e[4][4], n[4][4];
#pragma unroll
    for (int ch = 0; ch < 4; ++ch)
#pragma unroll
      for (int u = 0; u < 4; ++u)
        e[ch][u] = em[((size_t)((t0 + 2 * u + h) * B_DIM + bb + ch)) * 32 + r];
    for (int g = 0; g < 8; ++g) {
      int tg = t0 + 8 * (g + 1);
#pragma unroll
      for (int ch = 0; ch < 4; ++ch)
#pragma unroll
        for (int u = 0; u < 4; ++u) {
          int tt = tg + 2 * u + h; if (tt > T_DIM - 1) tt = T_DIM - 1;
          n[ch][u] = em[((size_t)(tt * B_DIM + bb + ch)) * 32 + r];
        }
#pragma unroll
      for (int u = 0; u < 4; ++u) {
        int sA = 8 * g + 2 * u, sB = sA + 1;
        float eA[4], eB[4];
#pragma unroll
        for (int ch = 0; ch < 4; ++ch) {
          float sw = __shfl_xor(e[ch][u], 32);
          eA[ch] = h ? sw : e[ch][u];
          eB[ch] = h ? e[ch][u] : sw;
        }
        step4(eA, sA);
        step4(eB, sB);
      }
#pragma unroll
      for (int ch = 0; ch < 4; ++ch) rescale(X[ch], off2[ch]);
#pragma unroll
      for (int ch = 0; ch < 4; ++ch)
#pragma unroll
        for (int u = 0; u < 4; ++u) e[ch][u] = n[ch][u];
    }
  } else {
    // ================= GENERAL PATH: per-step mask guards ===================
    float emv[4], emp[4];
#pragma unroll
    for (int ch = 0; ch < 4; ++ch)
      emv[ch] = em[((size_t)((t0 + h) * B_DIM + bb + ch)) * 32 + r];
    int tpf = t0 + 2 + h; if (tpf > T_DIM - 1) tpf = T_DIM - 1;
#pragma unroll
    for (int ch = 0; ch < 4; ++ch)
      emp[ch] = em[((size_t)(tpf * B_DIM + bb + ch)) * 32 + r];

    for (int it = 0; it < CLEN / 2; ++it) {
      int tn = t0 + 2 * it + 4 + h; if (tn > T_DIM - 1) tn = T_DIM - 1;
      float emn[4];
#pragma unroll
      for (int ch = 0; ch < 4; ++ch)
        emn[ch] = em[((size_t)(tn * B_DIM + bb + ch)) * 32 + r];

      int sA = 2 * it, sB = sA + 1;
#pragma unroll
      for (int ch = 0; ch < 4; ++ch) {
        float sw = __shfl_xor(emv[ch], 32);
        if ((mk[ch] >> sA) & 1)
          stepOne(X[ch], h ? sw : emv[ch], bcast_lane(rwv[ch], sA));
        if ((t0 + sB < t1) && ((mk[ch] >> sB) & 1))
          stepOne(X[ch], h ? emv[ch] : sw, bcast_lane(rwv[ch], sB));
      }

      if ((it & 3) == 3) {
#pragma unroll
        for (int ch = 0; ch < 4; ++ch) rescale(X[ch], off2[ch]);
      }
#pragma unroll
      for (int ch = 0; ch < 4; ++ch) { emv[ch] = emp[ch]; emp[ch] = emn[ch]; }
    }
  }

  // store X as packed bf16 row-pairs: mp[pair*32 + col] = (X[2p][col], X[2p+1][col])
#pragma unroll
  for (int ch = 0; ch < 4; ++ch) {
    uint32_t* mp = mats + (size_t)(u0 + ch) * 512;
#pragma unroll
    for (int u = 0; u < 8; ++u) {
      int pairIdx = (u & 1) + (u >> 1) * 4 + 2 * h;
      mp[pairIdx * 32 + r] = (uint32_t)pack_bf16(X[ch][2 * u], X[ch][2 * u + 1]);
    }
  }
  if (lane == 0) {
#pragma unroll
    for (int ch = 0; ch < 4; ++ch) offs[u0 + ch] = off2[ch];
  }

  // ---- score epilogue: one lane per timestep, all 4 chains ----
  int t = t0 + lane;
  float ssc = 0.f;
  if (t < t1) {
#pragma unroll
    for (int ch = 0; ch < 4; ++ch) {
      int b = bb + ch;
      int mkc  = mask[t * B_DIM + b];
      int mkn  = (t + 1 < T_DIM) ? mask[(t + 1) * B_DIM + b] : 0;
      int tg   = mkc ? tags[t * B_DIM + b] : 1;
      int mkp  = mask[(t - 1) * B_DIM + b];
      int tgp  = mkp ? tags[(t - 1) * B_DIM + b] : 1;
      if (mkc)
        ssc += em[(size_t)(t * B_DIM + b) * 32 + tg]
             + trans[tgp * 32 + tg] * __builtin_amdgcn_rcpf(wt[(t - 1) * B_DIM + b]);
      if (mkc && !mkn) ssc += endt[tg];
    }
  }
#pragma unroll
  for (int off = 32; off; off >>= 1) ssc += __shfl_xor(ssc, off);
  if (lane == 0) atomicAdd(out, -ssc);
}

// ---------------- combine chunks per batch + t=0 score ----------------
__global__ __launch_bounds__(64) void combine_kernel(
    const float* __restrict__ em, const int* __restrict__ tags,
    const int* __restrict__ mask, const float* __restrict__ startt,
    const float* __restrict__ endt, const uint32_t* __restrict__ mats,
    const float* __restrict__ offs, float* __restrict__ out)
{
  const float INV_LN2 = 1.44269504088896340736f;
  const float LN2 = 0.69314718055994530942f;
  int lane = threadIdx.x;
  int j = lane & 31;          // row handled by this lane (both halves hold av_j)
  int h = lane >> 5;          // which 16-column half this lane accumulates
  int b = blockIdx.x;
  int jp = j >> 1, jh = j & 1;

  float a0 = (startt[j] + em[(size_t)b * 32 + j]) * INV_LN2;  // log2 domain
  float c0 = a0;
#pragma unroll
  for (int off = 1; off < 32; off <<= 1) c0 = fmaxf(c0, __shfl_xor(c0, off));
  float av = __builtin_amdgcn_exp2f(a0 - c0);
  float acc = c0;  // accumulated log2 offset

  // depth-1 prefetch of chunk data
  const uint4* xr0 = (const uint4*)(mats + (size_t)b * 512 + jp * 32 + 16 * h);
  uint4 nv0 = xr0[0], nv1 = xr0[1];
  float noff = offs[b];

  for (int c = 0; c < CHUNKS; ++c) {
    uint4 v0 = nv0, v1 = nv1;
    float offc = noff;
    int cn = (c + 1 < CHUNKS) ? c + 1 : c;
    const uint4* xrn = (const uint4*)(mats + (size_t)(cn * B_DIM + b) * 512 + jp * 32 + 16 * h);
    nv0 = xrn[0]; nv1 = xrn[1];
    noff = offs[cn * B_DIM + b];

    float x[8];
    uint32_t u0[4] = {v0.x, v0.y, v0.z, v0.w};
    uint32_t u1[4] = {v1.x, v1.y, v1.z, v1.w};
#pragma unroll
    for (int e = 0; e < 4; ++e) {
      uint32_t bits0 = jh ? (u0[e] & 0xFFFF0000u) : (u0[e] << 16);
      uint32_t bits1 = jh ? (u1[e] & 0xFFFF0000u) : (u1[e] << 16);
      union { uint32_t uu; float f; } cv0, cv1;
      cv0.uu = bits0; cv1.uu = bits1;
      x[e] = cv0.f; x[4 + e] = cv1.f;
    }
    float s0 = 0.f, s1 = 0.f;
#pragma unroll
    for (int i = 0; i < 4; ++i) {
      s0 = fmaf(x[i],     __shfl(av, 16 * h + i),     s0);
      s1 = fmaf(x[4 + i], __shfl(av, 16 * h + 4 + i), s1);
    }
    float an = s0 + s1;
    an += __shfl_xor(an, 32);   // combine the two column-halves
    float mx = an;
#pragma unroll
    for (int off = 1; off < 32; off <<= 1) mx = fmaxf(mx, __shfl_xor(mx, off));
    av = an * __builtin_amdgcn_rcpf(mx);
    acc += __builtin_amdgcn_logf(mx) + offc;
  }

  float sv = av * __builtin_amdgcn_exp2f(endt[j] * INV_LN2);
#pragma unroll
  for (int off = 1; off < 32; off <<= 1) sv += __shfl_xor(sv, off);
  if (lane == 0) {
    float logZ = (acc + __builtin_amdgcn_logf(sv)) * LN2;
    // t=0 gold-path score terms
    int mk0 = mask[b];
    int tg0 = mk0 ? tags[b] : 1;
    float s0 = startt[tg0] + (mk0 ? em[(size_t)b * 32 + tg0] : 0.f);
    int mk1 = mask[B_DIM + b];
    if (mk0 && !mk1) s0 += endt[tg0];
    atomicAdd(out, logZ - s0);
  }
}

extern "C" void kernel_launch(void* const* d_in, const int* in_sizes, int n_in,
                              void* d_out, int out_size, void* d_ws, size_t ws_size,
                              hipStream_t stream) {
  const float* em   = (const float*)d_in[0];
  const int*   tags = (const int*)d_in[1];
  const float* wt   = (const float*)d_in[2];
  const int*   mask = (const int*)d_in[3];
  const float* tr   = (const float*)d_in[4];
  const float* stt  = (const float*)d_in[5];
  const float* ent  = (const float*)d_in[6];
  float* out = (float*)d_out;

  float* offs = (float*)d_ws;                          // CHUNKS*B floats (32 KB)
  uint32_t* mats = (uint32_t*)(offs + CHUNKS * B_DIM); // CHUNKS*B*512 u32 (~16.8 MB)

  (void)hipMemsetAsync(out, 0, sizeof(float) * out_size, stream);
  chunk_kernel<<<(CHUNKS * B_DIM) / 16, 256, 0, stream>>>(em, tags, wt, mask, tr, ent, mats, offs, out);
  combine_kernel<<<B_DIM, 64, 0, stream>>>(em, tags, mask, stt, ent, mats, offs, out);
}

// Round 17
// 176.915 us; speedup vs baseline: 1.8131x; 1.0135x over previous
//
#include <hip/hip_runtime.h>
#include <hip/hip_bf16.h>
#include <stdint.h>

// CRF nllh = sum_b (logZ_b - score_b).     TWO graph nodes (no memset node).
// logZ via chunked parallel scan in probability domain:
//   alpha_t = alpha_{t-1} * Q_t,  Q_t[i][j] = exp(trans[i][j]/w_{t-1} + em_t[j])
// 32 chunks of 64 steps: chunk computes X_c = (Q_{t0}..Q_{t1-1})^T with
// 32x32x16 bf16 MFMA pairs (X <- Q^T X, K=32 via C-chaining).
// k-permutation sigma folded into A-side constants => D reg-pairs ARE the next
// B operands verbatim. Q entries as bf16 BITS via magic-constant Schraudolph:
//   f = fma(tpre, 1/w, em*KSC + SBIAS + 2^23); bf16bits = low16(bits(f))
// ILP=4 phased step4 (A-builds -> B-packs -> 4 MFMA1 -> 4 MFMA2), LB(256,2),
// VGPR~76, chunk ~82us (reproduced R11/R15).
// NODE-COUNT REDUCTION: score partials plain-stored per wave (scoreP[wid]);
// ctrl counter zeroed by chunk blocks (identical-value race, ordered by the
// graph edge); combine blocks plain-store res[b], then ONE atomicAdd each --
// the last block (old==255) acquire-fences, sums res[]+scoreP[], plain-stores
// out[0]. No spinning (R14's spin barrier cost +140us -- banned). No atomics
// on out, no out-zeroing needed.
// Other negative results (do NOT revisit): ILP=8 spills; CHUNKS=64 -25%;
// depth-4 combine prefetch ring -30us; cross-wave TLP < in-wave ILP.

#define T_DIM 2048
#define B_DIM 256
#define M_DIM 32
#define CHUNKS 32
#define CLEN 64
#define NBLK ((CHUNKS * B_DIM) / 16)     /* 512 chunk blocks, 4 waves each */
#define KSC 184.6649652337873f      /* 128 / ln2 */
#define SBIAS2 12599160.66f         /* 2^23 + 127*128 - 7.34 (log-mean center) */

typedef __attribute__((ext_vector_type(8))) short short8;
typedef __attribute__((ext_vector_type(16))) float f32x16;

__device__ __forceinline__ int pack_bf16(float lo, float hi) {
  union { float f; uint32_t u; } a, b;
  a.f = lo; b.f = hi;
  // result = bf16(lo) | bf16(hi)<<16 (truncation rounding)
  return (int)__builtin_amdgcn_perm(b.u, a.u, 0x07060302u);
}

__device__ __forceinline__ int pack_lo16(int lo, int hi) {
  // (lo & 0xffff) | (hi << 16)
  return (int)__builtin_amdgcn_perm((uint32_t)hi, (uint32_t)lo, 0x05040100u);
}

__device__ __forceinline__ float bcast_lane(float v, int idx) {
  // wave-uniform broadcast: v_readlane -> SGPR (folds as scalar operand)
  return __int_as_float(__builtin_amdgcn_readlane(__float_as_int(v), idx));
}

// ---------------- chunk matrix products (MFMA) + score epilogue ----------------
// 256 threads = 4 waves; each wave handles units 4w..4w+3 (= chunk c,
// batches bb..bb+3).
__global__ __launch_bounds__(256, 2) void chunk_kernel(
    const float* __restrict__ em, const int* __restrict__ tags,
    const float* __restrict__ wt, const int* __restrict__ mask,
    const float* __restrict__ trans, const float* __restrict__ endt,
    uint32_t* __restrict__ mats, float* __restrict__ offs,
    float* __restrict__ scoreP, uint32_t* __restrict__ ctrl)
{
  int tid = threadIdx.x;
  if (tid == 0) ctrl[0] = 0;   // zero the combine counter (ordered by graph edge)
  int lane = tid & 63;
  int h = lane >> 5;        // wave half
  int r = lane & 31;        // A-row / B-col / D-col index
  int wid = blockIdx.x * 4 + (tid >> 6);
  int u0 = 4 * wid;                      // first unit = c*B + bb
  int bb = u0 & (B_DIM - 1);             // base batch (multiple of 4)
  int c = u0 >> 8;
  int t0 = 1 + c * CLEN;
  int t1 = t0 + CLEN; if (t1 > T_DIM) t1 = T_DIM;

  // A-side transition constants with the k-permutation sigma folded in:
  // sigma1(8h+j) = (j<4 ? j : j+4) + 4h ; sigma2 = sigma1 + 16  (shared chains)
  float tpre[16];
#pragma unroll
  for (int j = 0; j < 8; ++j) {
    int row = ((j < 4) ? j : j + 4) + 4 * h;
    tpre[j]     = trans[row * 32 + r] * KSC;
    tpre[8 + j] = trans[(row + 16) * 32 + r] * KSC;
  }

  // ---- hoisted per-chunk scalars: lane s <-> step t0+s ----
  int tw = t0 - 1 + lane; if (tw > T_DIM - 1) tw = T_DIM - 1;
  int tmk = t0 + lane; if (tmk > T_DIM - 1) tmk = T_DIM - 1;
  float rwv[4];
  uint64_t mk[4];
  uint64_t valid = (t1 - t0 >= 64) ? ~0ull : ((1ull << (t1 - t0)) - 1ull);
#pragma unroll
  for (int ch = 0; ch < 4; ++ch) {
    rwv[ch] = __builtin_amdgcn_rcpf(wt[tw * B_DIM + bb + ch]);
    mk[ch] = __ballot(mask[tmk * B_DIM + bb + ch] != 0) & valid;
  }

  // X = identity in 32x32 D/C layout: reg p holds row (p&3)+8*(p>>2)+4h, col r
  f32x16 X[4];
#pragma unroll
  for (int p = 0; p < 16; ++p) {
    float v = (((p & 3) + 8 * (p >> 2) + 4 * h) == r) ? 1.f : 0.f;
    X[0][p] = v; X[1][p] = v; X[2][p] = v; X[3][p] = v;
  }
  f32x16 z;
#pragma unroll
  for (int u = 0; u < 16; ++u) z[u] = 0.f;

  float off2[4] = {0.f, 0.f, 0.f, 0.f};

  // phased 4-chain step: A-builds, B-packs, MFMA1 x4, MFMA2 x4
  auto step4 = [&](const float* e4, int s) {
    float rw0 = bcast_lane(rwv[0], s), rw1 = bcast_lane(rwv[1], s);
    float rw2 = bcast_lane(rwv[2], s), rw3 = bcast_lane(rwv[3], s);
    float rw[4] = {rw0, rw1, rw2, rw3};
    union { int i[4]; short8 s8; } af1[4], af2[4], b1[4], b2[4];
    // Phase 1: A fragments (X-independent)
#pragma unroll
    for (int ch = 0; ch < 4; ++ch) {
      float e = fmaf(e4[ch], KSC, SBIAS2);
      float qf[16];
#pragma unroll
      for (int j = 0; j < 16; ++j)
        qf[j] = fmaf(tpre[j], rw[ch], e);
#pragma unroll
      for (int u = 0; u < 4; ++u) {
        af1[ch].i[u] = pack_lo16(__float_as_int(qf[2 * u]),     __float_as_int(qf[2 * u + 1]));
        af2[ch].i[u] = pack_lo16(__float_as_int(qf[8 + 2 * u]), __float_as_int(qf[8 + 2 * u + 1]));
      }
    }
    // Phase 2: B packs (X's D reg-pairs verbatim; sigma absorbed the mismatch)
#pragma unroll
    for (int ch = 0; ch < 4; ++ch)
#pragma unroll
      for (int u = 0; u < 4; ++u) {
        b1[ch].i[u] = pack_bf16(X[ch][2 * u],     X[ch][2 * u + 1]);
        b2[ch].i[u] = pack_bf16(X[ch][8 + 2 * u], X[ch][8 + 2 * u + 1]);
      }
    // Phase 3: MFMA1, all chains (independent)
    f32x16 d[4];
#pragma unroll
    for (int ch = 0; ch < 4; ++ch)
      d[ch] = __builtin_amdgcn_mfma_f32_32x32x16_bf16(af1[ch].s8, b1[ch].s8, z, 0, 0, 0);
    // Phase 4: MFMA2, all chains
#pragma unroll
    for (int ch = 0; ch < 4; ++ch)
      X[ch] = __builtin_amdgcn_mfma_f32_32x32x16_bf16(af2[ch].s8, b2[ch].s8, d[ch], 0, 0, 0);
  };

  auto stepOne = [&](f32x16& Xc, float e_em, float rw) {
    float e = fmaf(e_em, KSC, SBIAS2);
    float qf[16];
#pragma unroll
    for (int j = 0; j < 16; ++j)
      qf[j] = fmaf(tpre[j], rw, e);
    union { int i[4]; short8 s8; } af1, af2, b1_, b2_;
#pragma unroll
    for (int u = 0; u < 4; ++u) {
      af1.i[u] = pack_lo16(__float_as_int(qf[2 * u]),     __float_as_int(qf[2 * u + 1]));
      af2.i[u] = pack_lo16(__float_as_int(qf[8 + 2 * u]), __float_as_int(qf[8 + 2 * u + 1]));
      b1_.i[u] = pack_bf16(Xc[2 * u],     Xc[2 * u + 1]);
      b2_.i[u] = pack_bf16(Xc[8 + 2 * u], Xc[8 + 2 * u + 1]);
    }
    f32x16 d = __builtin_amdgcn_mfma_f32_32x32x16_bf16(af1.s8, b1_.s8, z, 0, 0, 0);
    Xc = __builtin_amdgcn_mfma_f32_32x32x16_bf16(af2.s8, b2_.s8, d, 0, 0, 0);
  };

  auto rescale = [&](f32x16& Xc, float& o2) {
    float mx = Xc[0];
#pragma unroll
    for (int u = 1; u < 16; ++u) mx = fmaxf(mx, Xc[u]);
#pragma unroll
    for (int off = 1; off < 64; off <<= 1) mx = fmaxf(mx, __shfl_xor(mx, off));
    float sc = __builtin_amdgcn_rcpf(mx);
    o2 += __builtin_amdgcn_logf(mx);  // log2
#pragma unroll
    for (int u = 0; u < 16; ++u) Xc[u] *= sc;
  };

  bool fast = (t1 - t0 == 64) && (mk[0] == ~0ull) && (mk[1] == ~0ull)
            && (mk[2] == ~0ull) && (mk[3] == ~0ull);

  if (fast) {
    // ================= FAST PATH: branch-free, groups of 8 steps ============
    float e[4][4], n[4][4];
#pragma unroll
    for (int ch = 0; ch < 4; ++ch)
#pragma unroll
      for (int u = 0; u < 4; ++u)
        e[ch][u] = em[((size_t)((t0 + 2 * u + h) * B_DIM + bb + ch)) * 32 + r];
    for (int g = 0; g < 8; ++g) {
      int tg = t0 + 8 * (g + 1);
#pragma unroll
      for (int ch = 0; ch < 4; ++ch)
#pragma unroll
        for (int u = 0; u < 4; ++u) {
          int tt = tg + 2 * u + h; if (tt > T_DIM - 1) tt = T_DIM - 1;
          n[ch][u] = em[((size_t)(tt * B_DIM + bb + ch)) * 32 + r];
        }
#pragma unroll
      for (int u = 0; u < 4; ++u) {
        int sA = 8 * g + 2 * u, sB = sA + 1;
        float eA[4], eB[4];
#pragma unroll
        for (int ch = 0; ch < 4; ++ch) {
          float sw = __shfl_xor(e[ch][u], 32);
          eA[ch] = h ? sw : e[ch][u];
          eB[ch] = h ? e[ch][u] : sw;
        }
        step4(eA, sA);
        step4(eB, sB);
      }
#pragma unroll
      for (int ch = 0; ch < 4; ++ch) rescale(X[ch], off2[ch]);
#pragma unroll
      for (int ch = 0; ch < 4; ++ch)
#pragma unroll
        for (int u = 0; u < 4; ++u) e[ch][u] = n[ch][u];
    }
  } else {
    // ================= GENERAL PATH: per-step mask guards ===================
    float emv[4], emp[4];
#pragma unroll
    for (int ch = 0; ch < 4; ++ch)
      emv[ch] = em[((size_t)((t0 + h) * B_DIM + bb + ch)) * 32 + r];
    int tpf = t0 + 2 + h; if (tpf > T_DIM - 1) tpf = T_DIM - 1;
#pragma unroll
    for (int ch = 0; ch < 4; ++ch)
      emp[ch] = em[((size_t)(tpf * B_DIM + bb + ch)) * 32 + r];

    for (int it = 0; it < CLEN / 2; ++it) {
      int tn = t0 + 2 * it + 4 + h; if (tn > T_DIM - 1) tn = T_DIM - 1;
      float emn[4];
#pragma unroll
      for (int ch = 0; ch < 4; ++ch)
        emn[ch] = em[((size_t)(tn * B_DIM + bb + ch)) * 32 + r];

      int sA = 2 * it, sB = sA + 1;
#pragma unroll
      for (int ch = 0; ch < 4; ++ch) {
        float sw = __shfl_xor(emv[ch], 32);
        if ((mk[ch] >> sA) & 1)
          stepOne(X[ch], h ? sw : emv[ch], bcast_lane(rwv[ch], sA));
        if ((t0 + sB < t1) && ((mk[ch] >> sB) & 1))
          stepOne(X[ch], h ? emv[ch] : sw, bcast_lane(rwv[ch], sB));
      }

      if ((it & 3) == 3) {
#pragma unroll
        for (int ch = 0; ch < 4; ++ch) rescale(X[ch], off2[ch]);
      }
#pragma unroll
      for (int ch = 0; ch < 4; ++ch) { emv[ch] = emp[ch]; emp[ch] = emn[ch]; }
    }
  }

  // store X as packed bf16 row-pairs: mp[pair*32 + col] = (X[2p][col], X[2p+1][col])
#pragma unroll
  for (int ch = 0; ch < 4; ++ch) {
    uint32_t* mp = mats + (size_t)(u0 + ch) * 512;
#pragma unroll
    for (int u = 0; u < 8; ++u) {
      int pairIdx = (u & 1) + (u >> 1) * 4 + 2 * h;
      mp[pairIdx * 32 + r] = (uint32_t)pack_bf16(X[ch][2 * u], X[ch][2 * u + 1]);
    }
  }
  if (lane == 0) {
#pragma unroll
    for (int ch = 0; ch < 4; ++ch) offs[u0 + ch] = off2[ch];
  }

  // ---- score epilogue: one lane per timestep, all 4 chains -> scoreP[wid] ----
  int t = t0 + lane;
  float ssc = 0.f;
  if (t < t1) {
#pragma unroll
    for (int ch = 0; ch < 4; ++ch) {
      int b = bb + ch;
      int mkc  = mask[t * B_DIM + b];
      int mkn  = (t + 1 < T_DIM) ? mask[(t + 1) * B_DIM + b] : 0;
      int tg   = mkc ? tags[t * B_DIM + b] : 1;
      int mkp  = mask[(t - 1) * B_DIM + b];
      int tgp  = mkp ? tags[(t - 1) * B_DIM + b] : 1;
      if (mkc)
        ssc += em[(size_t)(t * B_DIM + b) * 32 + tg]
             + trans[tgp * 32 + tg] * __builtin_amdgcn_rcpf(wt[(t - 1) * B_DIM + b]);
      if (mkc && !mkn) ssc += endt[tg];
    }
  }
#pragma unroll
  for (int off = 32; off; off >>= 1) ssc += __shfl_xor(ssc, off);
  if (lane == 0) scoreP[wid] = -ssc;
}

// ---------------- combine chunks per batch + t=0 score + final reduce ---------
__global__ __launch_bounds__(64) void combine_kernel(
    const float* __restrict__ em, const int* __restrict__ tags,
    const int* __restrict__ mask, const float* __restrict__ startt,
    const float* __restrict__ endt, const uint32_t* __restrict__ mats,
    const float* __restrict__ offs, const float* __restrict__ scoreP,
    float* __restrict__ res, uint32_t* __restrict__ ctrl,
    float* __restrict__ out)
{
  const float INV_LN2 = 1.44269504088896340736f;
  const float LN2 = 0.69314718055994530942f;
  int lane = threadIdx.x;
  int j = lane & 31;          // row handled by this lane (both halves hold av_j)
  int h = lane >> 5;          // which 16-column half this lane accumulates
  int b = blockIdx.x;
  int jp = j >> 1, jh = j & 1;

  float a0 = (startt[j] + em[(size_t)b * 32 + j]) * INV_LN2;  // log2 domain
  float c0 = a0;
#pragma unroll
  for (int off = 1; off < 32; off <<= 1) c0 = fmaxf(c0, __shfl_xor(c0, off));
  float av = __builtin_amdgcn_exp2f(a0 - c0);
  float acc = c0;  // accumulated log2 offset

  // depth-1 prefetch of chunk data
  const uint4* xr0 = (const uint4*)(mats + (size_t)b * 512 + jp * 32 + 16 * h);
  uint4 nv0 = xr0[0], nv1 = xr0[1];
  float noff = offs[b];

  for (int c = 0; c < CHUNKS; ++c) {
    uint4 v0 = nv0, v1 = nv1;
    float offc = noff;
    int cn = (c + 1 < CHUNKS) ? c + 1 : c;
    const uint4* xrn = (const uint4*)(mats + (size_t)(cn * B_DIM + b) * 512 + jp * 32 + 16 * h);
    nv0 = xrn[0]; nv1 = xrn[1];
    noff = offs[cn * B_DIM + b];

    float x[8];
    uint32_t u0[4] = {v0.x, v0.y, v0.z, v0.w};
    uint32_t u1[4] = {v1.x, v1.y, v1.z, v1.w};
#pragma unroll
    for (int e = 0; e < 4; ++e) {
      uint32_t bits0 = jh ? (u0[e] & 0xFFFF0000u) : (u0[e] << 16);
      uint32_t bits1 = jh ? (u1[e] & 0xFFFF0000u) : (u1[e] << 16);
      union { uint32_t uu; float f; } cv0, cv1;
      cv0.uu = bits0; cv1.uu = bits1;
      x[e] = cv0.f; x[4 + e] = cv1.f;
    }
    float s0 = 0.f, s1 = 0.f;
#pragma unroll
    for (int i = 0; i < 4; ++i) {
      s0 = fmaf(x[i],     __shfl(av, 16 * h + i),     s0);
      s1 = fmaf(x[4 + i], __shfl(av, 16 * h + 4 + i), s1);
    }
    float an = s0 + s1;
    an += __shfl_xor(an, 32);   // combine the two column-halves
    float mx = an;
#pragma unroll
    for (int off = 1; off < 32; off <<= 1) mx = fmaxf(mx, __shfl_xor(mx, off));
    av = an * __builtin_amdgcn_rcpf(mx);
    acc += __builtin_amdgcn_logf(mx) + offc;
  }

  float sv = av * __builtin_amdgcn_exp2f(endt[j] * INV_LN2);
#pragma unroll
  for (int off = 1; off < 32; off <<= 1) sv += __shfl_xor(sv, off);
  if (lane == 0) {
    float logZ = (acc + __builtin_amdgcn_logf(sv)) * LN2;
    // t=0 gold-path score terms
    int mk0 = mask[b];
    int tg0 = mk0 ? tags[b] : 1;
    float s0 = startt[tg0] + (mk0 ? em[(size_t)b * 32 + tg0] : 0.f);
    int mk1 = mask[B_DIM + b];
    if (mk0 && !mk1) s0 += endt[tg0];
    res[b] = logZ - s0;
  }

  // ---- last-block-done final reduction (no spinning) ----
  __builtin_amdgcn_fence(__ATOMIC_RELEASE, "agent");
  unsigned old = 0;
  if (lane == 0) old = atomicAdd(&ctrl[0], 1u);
  old = (unsigned)__shfl((int)old, 0);
  if (old == (unsigned)(B_DIM - 1)) {
    __builtin_amdgcn_fence(__ATOMIC_ACQUIRE, "agent");
    float s = 0.f;
#pragma unroll
    for (int i = 0; i < 4; ++i) s += res[lane + 64 * i];
#pragma unroll
    for (int i = 0; i < 32; ++i) s += scoreP[lane + 64 * i];
#pragma unroll
    for (int off = 32; off; off >>= 1) s += __shfl_xor(s, off);
    if (lane == 0) out[0] = s;
  }
}

extern "C" void kernel_launch(void* const* d_in, const int* in_sizes, int n_in,
                              void* d_out, int out_size, void* d_ws, size_t ws_size,
                              hipStream_t stream) {
  const float* em   = (const float*)d_in[0];
  const int*   tags = (const int*)d_in[1];
  const float* wt   = (const float*)d_in[2];
  const int*   mask = (const int*)d_in[3];
  const float* tr   = (const float*)d_in[4];
  const float* stt  = (const float*)d_in[5];
  const float* ent  = (const float*)d_in[6];
  float* out = (float*)d_out;

  uint32_t* ctrl  = (uint32_t*)d_ws;                    // [0]=counter (+pad to 16B)
  float* res      = (float*)d_ws + 4;                   // 256 floats
  float* scoreP   = res + B_DIM;                        // 2048 floats
  float* offs     = scoreP + 4 * NBLK;                  // CHUNKS*B floats (32 KB)
  uint32_t* mats  = (uint32_t*)(offs + CHUNKS * B_DIM); // CHUNKS*B*512 u32 (~16.8 MB)

  chunk_kernel<<<NBLK, 256, 0, stream>>>(em, tags, wt, mask, tr, ent,
                                         mats, offs, scoreP, ctrl);
  combine_kernel<<<B_DIM, 64, 0, stream>>>(em, tags, mask, stt, ent,
                                           mats, offs, scoreP, res, ctrl, out);
}